// Round 1
// baseline (385.226 us; speedup 1.0000x reference)
//
#include <hip/hip_runtime.h>

// Stream compaction:
//   mask[i]  = accept_index[i] >= 0
//   dst[i]   = exclusive_prefix_sum(mask)[i]
//   out[dst[i]] = out_cache_loc[accept_index[i]]  for mask[i]
//   out[total..N) = 0
//
// 3-pass scan (reduce -> scan-block-sums -> scatter) + tail-zero kernel.

#define N_TOTAL  16777216
#define BLOCK    256
#define EPT      16                   // elements per thread
#define TILE     (BLOCK * EPT)        // 4096
#define NBLOCKS  (N_TOTAL / TILE)     // 4096

// ---------------- pass 1: per-block count of accepted ----------------
__global__ __launch_bounds__(BLOCK) void k_reduce(const int* __restrict__ idx,
                                                  int* __restrict__ blockSums) {
    const int b = blockIdx.x;
    const int t = threadIdx.x;
    const int4* p = (const int4*)(idx + (size_t)b * TILE + (size_t)t * EPT);
    int cnt = 0;
#pragma unroll
    for (int j = 0; j < EPT / 4; ++j) {
        int4 v = p[j];
        cnt += (v.x >= 0) + (v.y >= 0) + (v.z >= 0) + (v.w >= 0);
    }
    // wave64 reduce
#pragma unroll
    for (int d = 32; d > 0; d >>= 1) cnt += __shfl_down(cnt, d);
    __shared__ int wsum[BLOCK / 64];
    const int lane = t & 63, wave = t >> 6;
    if (lane == 0) wsum[wave] = cnt;
    __syncthreads();
    if (t == 0) {
        int s = 0;
#pragma unroll
        for (int w = 0; w < BLOCK / 64; ++w) s += wsum[w];
        blockSums[b] = s;
    }
}

// ---------------- pass 2: exclusive scan of 4096 block sums (1 block) ----------------
__global__ __launch_bounds__(256) void k_scan(const int* __restrict__ blockSums,
                                              int* __restrict__ blockOffsets) {
    const int t = threadIdx.x;          // 256 threads x 16 values = 4096
    const int lane = t & 63, wave = t >> 6;
    int vals[16];
    const int4* p = (const int4*)(blockSums + t * 16);
#pragma unroll
    for (int j = 0; j < 4; ++j) {
        int4 v = p[j];
        vals[4 * j + 0] = v.x; vals[4 * j + 1] = v.y;
        vals[4 * j + 2] = v.z; vals[4 * j + 3] = v.w;
    }
    int tsum = 0;
#pragma unroll
    for (int j = 0; j < 16; ++j) tsum += vals[j];

    // inclusive wave scan of per-thread totals
    int x = tsum;
#pragma unroll
    for (int d = 1; d < 64; d <<= 1) {
        int y = __shfl_up(x, d);
        if (lane >= d) x += y;
    }
    __shared__ int wsum[4], woff[4];
    if (lane == 63) wsum[wave] = x;
    __syncthreads();
    if (t == 0) {
        int s = 0;
#pragma unroll
        for (int w = 0; w < 4; ++w) { woff[w] = s; s += wsum[w]; }
        blockOffsets[NBLOCKS] = s;   // grand total for tail-zero pass
    }
    __syncthreads();
    int run = (x - tsum) + woff[wave];   // exclusive prefix for this thread
#pragma unroll
    for (int j = 0; j < 16; ++j) {
        blockOffsets[t * 16 + j] = run;
        run += vals[j];
    }
}

// ---------------- pass 3: gather + scatter ----------------
__global__ __launch_bounds__(BLOCK) void k_scatter(const int* __restrict__ idx,
                                                   const float* __restrict__ src,
                                                   const int* __restrict__ blockOffsets,
                                                   float* __restrict__ out) {
    const int b = blockIdx.x;
    const int t = threadIdx.x;
    const int lane = t & 63, wave = t >> 6;
    const int4* p = (const int4*)(idx + (size_t)b * TILE + (size_t)t * EPT);
    int v[EPT];
#pragma unroll
    for (int j = 0; j < EPT / 4; ++j) {
        int4 q = p[j];
        v[4 * j + 0] = q.x; v[4 * j + 1] = q.y;
        v[4 * j + 2] = q.z; v[4 * j + 3] = q.w;
    }
    // gather unconditionally (safe index 0 for rejected) so all 16 loads are
    // in flight before any use -> latency hiding on the random gather
    float f[EPT];
#pragma unroll
    for (int j = 0; j < EPT; ++j) f[j] = src[v[j] < 0 ? 0 : v[j]];

    int cnt = 0;
#pragma unroll
    for (int j = 0; j < EPT; ++j) cnt += (v[j] >= 0);

    // block exclusive scan of per-thread counts
    int x = cnt;
#pragma unroll
    for (int d = 1; d < 64; d <<= 1) {
        int y = __shfl_up(x, d);
        if (lane >= d) x += y;
    }
    __shared__ int wsum[BLOCK / 64], woff[BLOCK / 64];
    if (lane == 63) wsum[wave] = x;
    __syncthreads();
    if (t == 0) {
        int s = 0;
#pragma unroll
        for (int w = 0; w < BLOCK / 64; ++w) { woff[w] = s; s += wsum[w]; }
    }
    __syncthreads();
    int dst = (x - cnt) + woff[wave] + blockOffsets[b];
#pragma unroll
    for (int j = 0; j < EPT; ++j) {
        if (v[j] >= 0) out[dst++] = f[j];
    }
}

// ---------------- pass 4: zero the tail [total, N) ----------------
__global__ __launch_bounds__(256) void k_tail(float* __restrict__ out,
                                              const int* __restrict__ total_p) {
    const int total = *total_p;
    const int i = (blockIdx.x * 256 + threadIdx.x) * 4;
    if (i >= total) {
        float4 z = make_float4(0.f, 0.f, 0.f, 0.f);
        *(float4*)(out + i) = z;
    } else if (i + 4 > total) {
#pragma unroll
        for (int k = 0; k < 4; ++k)
            if (i + k >= total) out[i + k] = 0.f;
    }
}

extern "C" void kernel_launch(void* const* d_in, const int* in_sizes, int n_in,
                              void* d_out, int out_size, void* d_ws, size_t ws_size,
                              hipStream_t stream) {
    const int*   idx = (const int*)d_in[0];     // accept_index (int32 per harness)
    const float* src = (const float*)d_in[1];   // out_cache_loc
    float*       out = (float*)d_out;

    int* blockSums    = (int*)d_ws;             // NBLOCKS ints
    int* blockOffsets = blockSums + NBLOCKS;    // NBLOCKS+1 ints (last = total)

    k_reduce <<<NBLOCKS, BLOCK, 0, stream>>>(idx, blockSums);
    k_scan   <<<1, 256, 0, stream>>>(blockSums, blockOffsets);
    k_scatter<<<NBLOCKS, BLOCK, 0, stream>>>(idx, src, blockOffsets, out);
    k_tail   <<<N_TOTAL / 4 / 256, 256, 0, stream>>>(out, blockOffsets + NBLOCKS);
}